// Round 3
// baseline (1569.713 us; speedup 1.0000x reference)
//
#include <hip/hip_runtime.h>
#include <hip/hip_fp16.h>
#include <math.h>

#define NN 50000
#define EE 800000
#define HIDF 128
#define NHEAD 8
#define OUTF 32
#define BN_EPS 1e-5f

typedef _Float16 half8_t __attribute__((ext_vector_type(8)));
typedef _Float16 half4_t __attribute__((ext_vector_type(4)));
typedef float float4_t __attribute__((ext_vector_type(4)));

// ---------------------------------------------------------------------------
// fp32 vector GEMM (embed layer 1 only: K=64 fp32 inputs)
// ---------------------------------------------------------------------------
__global__ __launch_bounds__(256)
void gemm_f32_k(const float* __restrict__ A, const float* __restrict__ B,
                float* __restrict__ C, int M) {
  constexpr int KDIM = 64, NC = 128, BM = 128, BK = 32;
  __shared__ float As[BK][BM + 4];
  __shared__ float Bs[BK][NC + 4];
  const int tid = threadIdx.x;
  const int tx = tid & 15, ty = tid >> 4;
  const int row0 = blockIdx.x * BM;
  float acc[8][8];
#pragma unroll
  for (int i = 0; i < 8; ++i)
#pragma unroll
    for (int j = 0; j < 8; ++j) acc[i][j] = 0.f;
  const int kq = tid & 7, rr = tid >> 3;
  for (int k0 = 0; k0 < KDIM; k0 += BK) {
#pragma unroll
    for (int i = 0; i < 4; ++i) {
      int r = rr + i * 32;
      int gr = row0 + r;
      float4 v = make_float4(0.f, 0.f, 0.f, 0.f);
      if (gr < M) v = *(const float4*)(A + (size_t)gr * KDIM + k0 + kq * 4);
      As[kq * 4 + 0][r] = v.x; As[kq * 4 + 1][r] = v.y;
      As[kq * 4 + 2][r] = v.z; As[kq * 4 + 3][r] = v.w;
    }
    {
      int bk = tid / 32, bc = tid % 32;
#pragma unroll
      for (int i = 0; i < 4; ++i) {
        int kk = bk + i * 8;
        *(float4*)&Bs[kk][bc * 4] =
            *(const float4*)(B + (size_t)(k0 + kk) * NC + bc * 4);
      }
    }
    __syncthreads();
#pragma unroll
    for (int k = 0; k < BK; ++k) {
      float a[8], b[8];
      *(float4*)&a[0] = *(const float4*)&As[k][ty * 8];
      *(float4*)&a[4] = *(const float4*)&As[k][ty * 8 + 4];
      *(float4*)&b[0] = *(const float4*)&Bs[k][tx * 8];
      *(float4*)&b[4] = *(const float4*)&Bs[k][tx * 8 + 4];
#pragma unroll
      for (int i = 0; i < 8; ++i)
#pragma unroll
        for (int j = 0; j < 8; ++j) acc[i][j] += a[i] * b[j];
    }
    __syncthreads();
  }
#pragma unroll
  for (int i = 0; i < 8; ++i) {
    int gr = row0 + ty * 8 + i;
    if (gr >= M) continue;
    size_t base = (size_t)gr * NC + tx * 8;
#pragma unroll
    for (int j = 0; j < 8; ++j) C[base + j] = acc[i][j];
  }
}

// ---------------------------------------------------------------------------
// MFMA f16 GEMM: C[M,NC] = A[M,128]@B[128,NC], Bt = B transposed [NC][128].
// 4 waves/block, wave = 32 rows x NC cols, 16x16x32 f16 MFMA, no LDS.
// ---------------------------------------------------------------------------
template <int NC, bool HEADMAJOR, bool F16OUT, bool F32OUT, bool RESID>
__global__ __launch_bounds__(256)
void mfma_gemm_k(const _Float16* __restrict__ A, const _Float16* __restrict__ Bt,
                 const float* __restrict__ resid, _Float16* __restrict__ Ch,
                 float* __restrict__ Cf, int M) {
  constexpr int NT = NC / 16;
  const int wave = threadIdx.x >> 6, lane = threadIdx.x & 63;
  const int q = lane >> 4, l16 = lane & 15;
  const int row0 = blockIdx.x * 128 + wave * 32;
  float4_t acc[2][NT];
#pragma unroll
  for (int i = 0; i < 2; ++i)
#pragma unroll
    for (int j = 0; j < NT; ++j) acc[i][j] = (float4_t){0.f, 0.f, 0.f, 0.f};
#pragma unroll
  for (int kk = 0; kk < 4; ++kk) {
    half8_t a[2];
#pragma unroll
    for (int i = 0; i < 2; ++i) {
      int r = row0 + i * 16 + l16;
      r = (r < M) ? r : (M - 1);
      a[i] = *(const half8_t*)(A + (size_t)r * 128 + kk * 32 + q * 8);
    }
#pragma unroll
    for (int j = 0; j < NT; ++j) {
      half8_t b = *(const half8_t*)(Bt + (size_t)(j * 16 + l16) * 128 + kk * 32 + q * 8);
      acc[0][j] = __builtin_amdgcn_mfma_f32_16x16x32_f16(a[0], b, acc[0][j], 0, 0, 0);
      acc[1][j] = __builtin_amdgcn_mfma_f32_16x16x32_f16(a[1], b, acc[1][j], 0, 0, 0);
    }
  }
#pragma unroll
  for (int i = 0; i < 2; ++i)
#pragma unroll
    for (int j = 0; j < NT; ++j)
#pragma unroll
      for (int r = 0; r < 4; ++r) {
        int row = row0 + i * 16 + q * 4 + r;   // C/D: row=(lane>>4)*4+reg
        if (row >= M) continue;
        int col = j * 16 + l16;                // col=lane&15
        float v = acc[i][j][r];
        if constexpr (RESID) v += resid[(size_t)row * NC + col];
        if constexpr (F32OUT) Cf[(size_t)row * NC + col] = v;
        if constexpr (F16OUT) {
          size_t o = HEADMAJOR
              ? ((size_t)(col >> 4) * (size_t)M * 16 + (size_t)row * 16 + (col & 15))
              : ((size_t)row * NC + col);
          Ch[o] = (_Float16)v;
        }
      }
}

// ---------------------------------------------------------------------------
// weight transpose + fp32->fp16 convert (11 small matrices, one launch)
// ---------------------------------------------------------------------------
struct TJob { const float* src; _Float16* dst; int k, n; };
struct TJobs { TJob j[11]; };

__global__ __launch_bounds__(256)
void transpose_k(TJobs jobs) {
  TJob job = jobs.j[blockIdx.x];
  int total = job.k * job.n;
  for (int i = threadIdx.x; i < total; i += 256) {
    int kk = i / job.n, nn = i % job.n;
    job.dst[(size_t)nn * job.k + kk] = (_Float16)job.src[i];
  }
}

// ---------------------------------------------------------------------------
// BatchNorm
// ---------------------------------------------------------------------------
__global__ __launch_bounds__(256)
void bn_stats_k(const float* __restrict__ Y, float* __restrict__ stats, int M) {
  __shared__ float sh[256], sq[256];
  int col = threadIdx.x & 127;
  int half = threadIdx.x >> 7;
  int start = blockIdx.x * 64;
  int end = min(start + 64, M);
  float s = 0.f, qq = 0.f;
  for (int r = start + half; r < end; r += 2) {
    float v = Y[(size_t)r * 128 + col];
    s += v; qq += v * v;
  }
  sh[threadIdx.x] = s; sq[threadIdx.x] = qq;
  __syncthreads();
  if (half == 0) {
    s = sh[threadIdx.x] + sh[threadIdx.x + 128];
    qq = sq[threadIdx.x] + sq[threadIdx.x + 128];
    atomicAdd(&stats[col], s);
    atomicAdd(&stats[128 + col], qq);
  }
}

__global__ void bn_final_k(float* stats, const float* __restrict__ gamma,
                           const float* __restrict__ beta) {
  int c = threadIdx.x;  // 128 threads
  float mean = stats[c] * (1.f / NN);
  float var = stats[128 + c] * (1.f / NN) - mean * mean;
  var = fmaxf(var, 0.f);
  float sc = gamma[c] * rsqrtf(var + BN_EPS);
  stats[256 + c] = sc;
  stats[384 + c] = beta[c] - mean * sc;
}

__global__ __launch_bounds__(256)
void bn_apply_k(const float* __restrict__ Y, const float* __restrict__ stats,
                float* __restrict__ H, _Float16* __restrict__ Hh, int M) {
  size_t i = (size_t)blockIdx.x * 256 + threadIdx.x;  // over M*32 float4s
  if (i >= (size_t)M * 32) return;
  int c4 = (int)(i & 31) * 4;
  float4 y = ((const float4*)Y)[i];
  float4 h;
  h.x = fmaxf(y.x * stats[256 + c4 + 0] + stats[384 + c4 + 0], 0.f);
  h.y = fmaxf(y.y * stats[256 + c4 + 1] + stats[384 + c4 + 1], 0.f);
  h.z = fmaxf(y.z * stats[256 + c4 + 2] + stats[384 + c4 + 2], 0.f);
  h.w = fmaxf(y.w * stats[256 + c4 + 3] + stats[384 + c4 + 3], 0.f);
  ((float4*)H)[i] = h;
  half4_t hh = {(_Float16)h.x, (_Float16)h.y, (_Float16)h.z, (_Float16)h.w};
  ((half4_t*)Hh)[i] = hh;
}

// ---------------------------------------------------------------------------
// attention logits from head-major fp16 feat; el/er stored head-major [8][NN]
// ---------------------------------------------------------------------------
__global__ __launch_bounds__(256)
void eler_k(const _Float16* __restrict__ feat, const float* __restrict__ al,
            const float* __restrict__ ar, float* __restrict__ el,
            float* __restrict__ er) {
  int h = blockIdx.y;
  int n = blockIdx.x * 256 + threadIdx.x;
  if (n >= NN) return;
  const _Float16* f = feat + (size_t)h * NN * 16 + (size_t)n * 16;
  half8_t f0 = *(const half8_t*)f;
  half8_t f1 = *(const half8_t*)(f + 8);
  float sl = 0.f, sr = 0.f;
#pragma unroll
  for (int d = 0; d < 8; ++d) {
    sl += (float)f0[d] * al[h * 16 + d] + (float)f1[d] * al[h * 16 + 8 + d];
    sr += (float)f0[d] * ar[h * 16 + d] + (float)f1[d] * ar[h * 16 + 8 + d];
  }
  el[(size_t)h * NN + n] = sl;
  er[(size_t)h * NN + n] = sr;
}

// ---------------------------------------------------------------------------
// CSR build
// ---------------------------------------------------------------------------
__global__ __launch_bounds__(256)
void hist_k(const int* __restrict__ dst, int* __restrict__ deg) {
  int e = blockIdx.x * 256 + threadIdx.x;
  if (e < EE) atomicAdd(&deg[dst[e]], 1);
}

__global__ __launch_bounds__(256)
void scan_block_k(const int* __restrict__ in, int* __restrict__ out,
                  int* __restrict__ bsums, int n) {
  __shared__ int sh[256];
  int i = blockIdx.x * 256 + threadIdx.x;
  int v = (i < n) ? in[i] : 0;
  sh[threadIdx.x] = v;
  __syncthreads();
#pragma unroll
  for (int off = 1; off < 256; off <<= 1) {
    int t = (threadIdx.x >= off) ? sh[threadIdx.x - off] : 0;
    __syncthreads();
    sh[threadIdx.x] += t;
    __syncthreads();
  }
  if (i < n) out[i] = sh[threadIdx.x] - v;  // exclusive
  if (threadIdx.x == 255) bsums[blockIdx.x] = sh[255];
}

__global__ __launch_bounds__(256)
void scan_bsums_k(int* bsums, int nb) {
  __shared__ int sh[256];
  int v = (threadIdx.x < nb) ? bsums[threadIdx.x] : 0;
  sh[threadIdx.x] = v;
  __syncthreads();
#pragma unroll
  for (int off = 1; off < 256; off <<= 1) {
    int t = (threadIdx.x >= off) ? sh[threadIdx.x - off] : 0;
    __syncthreads();
    sh[threadIdx.x] += t;
    __syncthreads();
  }
  if (threadIdx.x < nb) bsums[threadIdx.x] = sh[threadIdx.x] - v;
}

__global__ __launch_bounds__(256)
void add_off_k(int* __restrict__ out, const int* __restrict__ bsums, int n) {
  int i = blockIdx.x * 256 + threadIdx.x;
  if (i < n) out[i] += bsums[blockIdx.x];
  if (i == 0) out[n] = EE;
}

__global__ __launch_bounds__(256)
void fill_k(const int* __restrict__ src, const int* __restrict__ dst,
            const int* __restrict__ rowptr, int* __restrict__ cnt,
            int* __restrict__ csrsrc) {
  int e = blockIdx.x * 256 + threadIdx.x;
  if (e >= EE) return;
  int d = dst[e];
  int p = rowptr[d] + atomicAdd(&cnt[d], 1);
  csrsrc[p] = src[e];
}

// ---------------------------------------------------------------------------
// GAT aggregate, head-sliced: block handles head (blockIdx&7) -> XCD-local L2
// working set (feat slice 1.6MB/rel + el/er). 16-lane group per node, 4 nodes
// interleaved for MLP; branch-free predicated online softmax.
// ---------------------------------------------------------------------------
__device__ __forceinline__ void agg_rel4(
    const _Float16* __restrict__ feat, const float* __restrict__ el,
    const float* __restrict__ er, const int* __restrict__ rp,
    const int* __restrict__ cs, int h, int ln, const int n[4], float r[4]) {
  int beg[4], len[4];
  float erh[4];
#pragma unroll
  for (int j = 0; j < 4; ++j) {
    bool v = n[j] < NN;
    int nb = v ? n[j] : 0;
    beg[j] = rp[nb];
    len[j] = v ? (rp[nb + 1] - beg[j]) : 0;
    erh[j] = er[(size_t)h * NN + nb];
  }
  int maxlen = max(max(len[0], len[1]), max(len[2], len[3]));
  float m[4], ls[4], ac[4];
#pragma unroll
  for (int j = 0; j < 4; ++j) { m[j] = -1e30f; ls[j] = 0.f; ac[j] = 0.f; }
  for (int t = 0; t < maxlen; ++t) {
    int s[4];
#pragma unroll
    for (int j = 0; j < 4; ++j) {
      int idx = (t < len[j]) ? beg[j] + t : 0;
      s[j] = cs[idx];
    }
    float ev[4], fv[4];
#pragma unroll
    for (int j = 0; j < 4; ++j) {
      ev[j] = el[(size_t)h * NN + s[j]];
      fv[j] = (float)feat[(size_t)h * NN * 16 + (size_t)s[j] * 16 + ln];
    }
#pragma unroll
    for (int j = 0; j < 4; ++j) {
      bool act = t < len[j];
      float x = ev[j] + erh[j];
      x = (x > 0.f) ? x : 0.2f * x;            // leaky_relu 0.2
      float mn = act ? fmaxf(m[j], x) : m[j];
      float scl = __expf(m[j] - mn);           // inactive: exp(0)=1 (no-op)
      float p = act ? __expf(x - mn) : 0.f;
      ls[j] = ls[j] * scl + p;
      ac[j] = ac[j] * scl + p * fv[j];
      m[j] = mn;
    }
  }
#pragma unroll
  for (int j = 0; j < 4; ++j) r[j] = (len[j] > 0) ? ac[j] / ls[j] : 0.f;
}

__global__ __launch_bounds__(256)
void gat_agg_k(const _Float16* __restrict__ f0, const _Float16* __restrict__ f1,
               const float* __restrict__ el0, const float* __restrict__ er0,
               const float* __restrict__ el1, const float* __restrict__ er1,
               const int* __restrict__ rp0, const int* __restrict__ cs0,
               const int* __restrict__ rp1, const int* __restrict__ cs1,
               const float* __restrict__ b0, const float* __restrict__ b1,
               float* __restrict__ h1, _Float16* __restrict__ h1h) {
  int h = blockIdx.x & 7;          // XCD-aligned head slice
  int chunk = blockIdx.x >> 3;
  int g = threadIdx.x >> 4, ln = threadIdx.x & 15;
  int n[4];
#pragma unroll
  for (int j = 0; j < 4; ++j) n[j] = chunk * 64 + j * 16 + g;
  float r0[4], r1[4];
  agg_rel4(f0, el0, er0, rp0, cs0, h, ln, n, r0);
  agg_rel4(f1, el1, er1, rp1, cs1, h, ln, n, r1);
  float bb = b0[h * 16 + ln] + b1[h * 16 + ln];
#pragma unroll
  for (int j = 0; j < 4; ++j) {
    if (n[j] >= NN) continue;
    float t = r0[j] + r1[j] + bb;
    t = (t > 0.f) ? t : 0.01f * t;             // leaky_relu 0.01
    size_t o = (size_t)n[j] * 128 + h * 16 + ln;
    float nh = h1[o] + t;
    h1[o] = nh;
    h1h[o] = (_Float16)nh;
  }
}

// ---------------------------------------------------------------------------
extern "C" void kernel_launch(void* const* d_in, const int* in_sizes, int n_in,
                              void* d_out, int out_size, void* d_ws,
                              size_t ws_size, hipStream_t stream) {
  const float* inputs = (const float*)d_in[0];
  const int* src = (const int*)d_in[1];
  const int* dst = (const int*)d_in[2];
  const float* ew1 = (const float*)d_in[3];
  const float* eg = (const float*)d_in[4];
  const float* eb = (const float*)d_in[5];
  const float* ew2 = (const float*)d_in[6];
  const float* gfc = (const float*)d_in[7];
  const float* gal = (const float*)d_in[8];
  const float* gar = (const float*)d_in[9];
  const float* gb = (const float*)d_in[10];
  const float* dw1 = (const float*)d_in[11];
  const float* dg = (const float*)d_in[12];
  const float* db = (const float*)d_in[13];
  const float* dw2 = (const float*)d_in[14];
  float* out = (float*)d_out;

  // ---- workspace layout (~84 MB) ----
  char* p = (char*)d_ws;
  float* h1 = (float*)p;            p += (size_t)NN * 128 * 4;   // 25.6MB
  _Float16* h1h = (_Float16*)p;     p += (size_t)NN * 128 * 2;   // 12.8MB
  // region C (25.6MB): ybuf (MLP phases) | feat0h+feat1h (GAT phase)
  float* ybuf = (float*)p;
  _Float16* feat0h = (_Float16*)p;
  _Float16* feat1h = feat0h + (size_t)NN * 128;
  p += (size_t)NN * 128 * 4;
  // region D (12.8MB): ybuf_h (MLP phases) | el/er (GAT phase)
  _Float16* ybuf_h = (_Float16*)p;
  float* el0 = (float*)p;
  float* er0 = el0 + (size_t)NHEAD * NN;
  float* el1 = er0 + (size_t)NHEAD * NN;
  float* er1 = el1 + (size_t)NHEAD * NN;
  p += (size_t)NN * 128 * 2;
  float* stats = (float*)p;         p += 512 * 4;
  _Float16* wt = (_Float16*)p;      p += (size_t)(10 * 16384 + 4096) * 2;
  _Float16* ew2t = wt;
  _Float16* dw1t = wt + 9 * 16384;
  _Float16* dw2t = wt + 10 * 16384;
  int* rowptr0 = (int*)p;           p += (NN + 1) * 4;
  int* rowptr1 = (int*)p;           p += (NN + 1) * 4;
  int* csr0 = (int*)p;              p += (size_t)EE * 4;
  int* csr1 = (int*)p;              p += (size_t)EE * 4;
  int* cnt = (int*)p;               p += NN * 4;
  int* bsums = (int*)p;
  int* rowptr[2] = {rowptr0, rowptr1};
  int* csr[2] = {csr0, csr1};

  const int SCB = (NN + 255) / 256;   // 196
  const int EGB = (EE + 255) / 256;   // 3125
  const int GB = (NN + 127) / 128;    // 391

  // ---- CSR build per relation ----
  for (int r = 0; r < 2; ++r) {
    hipMemsetAsync(cnt, 0, NN * sizeof(int), stream);
    hist_k<<<EGB, 256, 0, stream>>>(dst + (size_t)r * EE, cnt);
    scan_block_k<<<SCB, 256, 0, stream>>>(cnt, rowptr[r], bsums, NN);
    scan_bsums_k<<<1, 256, 0, stream>>>(bsums, SCB);
    add_off_k<<<SCB, 256, 0, stream>>>(rowptr[r], bsums, NN);
    hipMemsetAsync(cnt, 0, NN * sizeof(int), stream);
    fill_k<<<EGB, 256, 0, stream>>>(src + (size_t)r * EE, dst + (size_t)r * EE,
                                    rowptr[r], cnt, csr[r]);
  }

  // ---- transpose+convert all 11 weight matrices (one launch) ----
  {
    TJobs jobs;
    jobs.j[0] = {ew2, ew2t, 128, 128};
    for (int i = 0; i < 8; ++i)
      jobs.j[1 + i] = {gfc + (size_t)i * 16384, wt + (size_t)(1 + i) * 16384, 128, 128};
    jobs.j[9] = {dw1, dw1t, 128, 128};
    jobs.j[10] = {dw2, dw2t, 128, 32};
    transpose_k<<<11, 256, 0, stream>>>(jobs);
  }

  // ---- embed MLP: h = relu(bn(x@w1)); h1 = h@w2 + h ----
  gemm_f32_k<<<GB, 256, 0, stream>>>(inputs, ew1, ybuf, NN);
  hipMemsetAsync(stats, 0, 512 * sizeof(float), stream);
  bn_stats_k<<<(NN + 63) / 64, 256, 0, stream>>>(ybuf, stats, NN);
  bn_final_k<<<1, 128, 0, stream>>>(stats, eg, eb);
  bn_apply_k<<<(NN * 32 + 255) / 256, 256, 0, stream>>>(ybuf, stats, ybuf, ybuf_h, NN);
  mfma_gemm_k<128, false, true, true, true><<<GB, 256, 0, stream>>>(
      ybuf_h, ew2t, ybuf, h1h, h1, NN);

  // ---- 4 GAT layers ----
  for (int l = 0; l < 4; ++l) {
    _Float16* wt0 = wt + (size_t)(1 + l * 2 + 0) * 16384;
    _Float16* wt1 = wt + (size_t)(1 + l * 2 + 1) * 16384;
    mfma_gemm_k<128, true, true, false, false><<<GB, 256, 0, stream>>>(
        h1h, wt0, nullptr, feat0h, nullptr, NN);
    mfma_gemm_k<128, true, true, false, false><<<GB, 256, 0, stream>>>(
        h1h, wt1, nullptr, feat1h, nullptr, NN);
    eler_k<<<dim3(SCB, 8), 256, 0, stream>>>(
        feat0h, gal + (size_t)(l * 2 + 0) * HIDF,
        gar + (size_t)(l * 2 + 0) * HIDF, el0, er0);
    eler_k<<<dim3(SCB, 8), 256, 0, stream>>>(
        feat1h, gal + (size_t)(l * 2 + 1) * HIDF,
        gar + (size_t)(l * 2 + 1) * HIDF, el1, er1);
    gat_agg_k<<<8 * ((NN + 63) / 64), 256, 0, stream>>>(
        feat0h, feat1h, el0, er0, el1, er1, rowptr[0], csr[0], rowptr[1],
        csr[1], gb + (size_t)(l * 2 + 0) * HIDF,
        gb + (size_t)(l * 2 + 1) * HIDF, h1, h1h);
  }

  // ---- decision MLP: out = relu(bn(h1@w1)) @ w2 ----
  mfma_gemm_k<128, false, false, true, false><<<GB, 256, 0, stream>>>(
      h1h, dw1t, nullptr, nullptr, ybuf, NN);
  hipMemsetAsync(stats, 0, 512 * sizeof(float), stream);
  bn_stats_k<<<(NN + 63) / 64, 256, 0, stream>>>(ybuf, stats, NN);
  bn_final_k<<<1, 128, 0, stream>>>(stats, dg, db);
  bn_apply_k<<<(NN * 32 + 255) / 256, 256, 0, stream>>>(ybuf, stats, ybuf, ybuf_h, NN);
  mfma_gemm_k<32, false, false, true, false><<<GB, 256, 0, stream>>>(
      ybuf_h, dw2t, nullptr, nullptr, out, NN);
}

// Round 4
// 996.640 us; speedup vs baseline: 1.5750x; 1.5750x over previous
//
#include <hip/hip_runtime.h>
#include <hip/hip_fp16.h>
#include <math.h>

#define NN 50000
#define EE 800000
#define HIDF 128
#define NHEAD 8
#define OUTF 32
#define BN_EPS 1e-5f

typedef _Float16 half8_t __attribute__((ext_vector_type(8)));
typedef _Float16 half4_t __attribute__((ext_vector_type(4)));
typedef float float4_t __attribute__((ext_vector_type(4)));

// ---------------------------------------------------------------------------
// fp32 vector GEMM (embed layer 1 only: K=64 fp32 inputs)
// ---------------------------------------------------------------------------
__global__ __launch_bounds__(256)
void gemm_f32_k(const float* __restrict__ A, const float* __restrict__ B,
                float* __restrict__ C, int M) {
  constexpr int KDIM = 64, NC = 128, BM = 128, BK = 32;
  __shared__ float As[BK][BM + 4];
  __shared__ float Bs[BK][NC + 4];
  const int tid = threadIdx.x;
  const int tx = tid & 15, ty = tid >> 4;
  const int row0 = blockIdx.x * BM;
  float acc[8][8];
#pragma unroll
  for (int i = 0; i < 8; ++i)
#pragma unroll
    for (int j = 0; j < 8; ++j) acc[i][j] = 0.f;
  const int kq = tid & 7, rr = tid >> 3;
  for (int k0 = 0; k0 < KDIM; k0 += BK) {
#pragma unroll
    for (int i = 0; i < 4; ++i) {
      int r = rr + i * 32;
      int gr = row0 + r;
      float4 v = make_float4(0.f, 0.f, 0.f, 0.f);
      if (gr < M) v = *(const float4*)(A + (size_t)gr * KDIM + k0 + kq * 4);
      As[kq * 4 + 0][r] = v.x; As[kq * 4 + 1][r] = v.y;
      As[kq * 4 + 2][r] = v.z; As[kq * 4 + 3][r] = v.w;
    }
    {
      int bk = tid / 32, bc = tid % 32;
#pragma unroll
      for (int i = 0; i < 4; ++i) {
        int kk = bk + i * 8;
        *(float4*)&Bs[kk][bc * 4] =
            *(const float4*)(B + (size_t)(k0 + kk) * NC + bc * 4);
      }
    }
    __syncthreads();
#pragma unroll
    for (int k = 0; k < BK; ++k) {
      float a[8], b[8];
      *(float4*)&a[0] = *(const float4*)&As[k][ty * 8];
      *(float4*)&a[4] = *(const float4*)&As[k][ty * 8 + 4];
      *(float4*)&b[0] = *(const float4*)&Bs[k][tx * 8];
      *(float4*)&b[4] = *(const float4*)&Bs[k][tx * 8 + 4];
#pragma unroll
      for (int i = 0; i < 8; ++i)
#pragma unroll
        for (int j = 0; j < 8; ++j) acc[i][j] += a[i] * b[j];
    }
    __syncthreads();
  }
#pragma unroll
  for (int i = 0; i < 8; ++i) {
    int gr = row0 + ty * 8 + i;
    if (gr >= M) continue;
    size_t base = (size_t)gr * NC + tx * 8;
#pragma unroll
    for (int j = 0; j < 8; ++j) C[base + j] = acc[i][j];
  }
}

// ---------------------------------------------------------------------------
// MFMA f16 GEMM: C[M,NC] = A[M,128]@B[128,NC], Bt = B transposed [NC][128].
// 4 waves/block, wave = 32 rows x NC cols, 16x16x32 f16 MFMA, no LDS.
// ---------------------------------------------------------------------------
template <int NC, bool F16OUT, bool F32OUT, bool RESID>
__global__ __launch_bounds__(256)
void mfma_gemm_k(const _Float16* __restrict__ A, const _Float16* __restrict__ Bt,
                 const float* __restrict__ resid, _Float16* __restrict__ Ch,
                 float* __restrict__ Cf, int M) {
  constexpr int NT = NC / 16;
  const int wave = threadIdx.x >> 6, lane = threadIdx.x & 63;
  const int q = lane >> 4, l16 = lane & 15;
  const int row0 = blockIdx.x * 128 + wave * 32;
  float4_t acc[2][NT];
#pragma unroll
  for (int i = 0; i < 2; ++i)
#pragma unroll
    for (int j = 0; j < NT; ++j) acc[i][j] = (float4_t){0.f, 0.f, 0.f, 0.f};
#pragma unroll
  for (int kk = 0; kk < 4; ++kk) {
    half8_t a[2];
#pragma unroll
    for (int i = 0; i < 2; ++i) {
      int r = row0 + i * 16 + l16;
      r = (r < M) ? r : (M - 1);
      a[i] = *(const half8_t*)(A + (size_t)r * 128 + kk * 32 + q * 8);
    }
#pragma unroll
    for (int j = 0; j < NT; ++j) {
      half8_t b = *(const half8_t*)(Bt + (size_t)(j * 16 + l16) * 128 + kk * 32 + q * 8);
      acc[0][j] = __builtin_amdgcn_mfma_f32_16x16x32_f16(a[0], b, acc[0][j], 0, 0, 0);
      acc[1][j] = __builtin_amdgcn_mfma_f32_16x16x32_f16(a[1], b, acc[1][j], 0, 0, 0);
    }
  }
#pragma unroll
  for (int i = 0; i < 2; ++i)
#pragma unroll
    for (int j = 0; j < NT; ++j)
#pragma unroll
      for (int r = 0; r < 4; ++r) {
        int row = row0 + i * 16 + q * 4 + r;   // C/D: row=(lane>>4)*4+reg
        if (row >= M) continue;
        int col = j * 16 + l16;                // col=lane&15
        float v = acc[i][j][r];
        if constexpr (RESID) v += resid[(size_t)row * NC + col];
        if constexpr (F32OUT) Cf[(size_t)row * NC + col] = v;
        if constexpr (F16OUT) Ch[(size_t)row * NC + col] = (_Float16)v;
      }
}

// ---------------------------------------------------------------------------
// weight transpose + fp32->fp16 convert (11 small matrices, one launch)
// ---------------------------------------------------------------------------
struct TJob { const float* src; _Float16* dst; int k, n; };
struct TJobs { TJob j[11]; };

__global__ __launch_bounds__(256)
void transpose_k(TJobs jobs) {
  TJob job = jobs.j[blockIdx.x];
  int total = job.k * job.n;
  for (int i = threadIdx.x; i < total; i += 256) {
    int kk = i / job.n, nn = i % job.n;
    job.dst[(size_t)nn * job.k + kk] = (_Float16)job.src[i];
  }
}

// ---------------------------------------------------------------------------
// BatchNorm
// ---------------------------------------------------------------------------
__global__ __launch_bounds__(256)
void bn_stats_k(const float* __restrict__ Y, float* __restrict__ stats, int M) {
  __shared__ float sh[256], sq[256];
  int col = threadIdx.x & 127;
  int half = threadIdx.x >> 7;
  int start = blockIdx.x * 64;
  int end = min(start + 64, M);
  float s = 0.f, qq = 0.f;
  for (int r = start + half; r < end; r += 2) {
    float v = Y[(size_t)r * 128 + col];
    s += v; qq += v * v;
  }
  sh[threadIdx.x] = s; sq[threadIdx.x] = qq;
  __syncthreads();
  if (half == 0) {
    s = sh[threadIdx.x] + sh[threadIdx.x + 128];
    qq = sq[threadIdx.x] + sq[threadIdx.x + 128];
    atomicAdd(&stats[col], s);
    atomicAdd(&stats[128 + col], qq);
  }
}

__global__ void bn_final_k(float* stats, const float* __restrict__ gamma,
                           const float* __restrict__ beta) {
  int c = threadIdx.x;  // 128 threads
  float mean = stats[c] * (1.f / NN);
  float var = stats[128 + c] * (1.f / NN) - mean * mean;
  var = fmaxf(var, 0.f);
  float sc = gamma[c] * rsqrtf(var + BN_EPS);
  stats[256 + c] = sc;
  stats[384 + c] = beta[c] - mean * sc;
}

__global__ __launch_bounds__(256)
void bn_apply_k(const float* __restrict__ Y, const float* __restrict__ stats,
                float* __restrict__ H, _Float16* __restrict__ Hh, int M) {
  size_t i = (size_t)blockIdx.x * 256 + threadIdx.x;  // over M*32 float4s
  if (i >= (size_t)M * 32) return;
  int c4 = (int)(i & 31) * 4;
  float4 y = ((const float4*)Y)[i];
  float4 h;
  h.x = fmaxf(y.x * stats[256 + c4 + 0] + stats[384 + c4 + 0], 0.f);
  h.y = fmaxf(y.y * stats[256 + c4 + 1] + stats[384 + c4 + 1], 0.f);
  h.z = fmaxf(y.z * stats[256 + c4 + 2] + stats[384 + c4 + 2], 0.f);
  h.w = fmaxf(y.w * stats[256 + c4 + 3] + stats[384 + c4 + 3], 0.f);
  ((float4*)H)[i] = h;
  half4_t hh = {(_Float16)h.x, (_Float16)h.y, (_Float16)h.z, (_Float16)h.w};
  ((half4_t*)Hh)[i] = hh;
}

// ---------------------------------------------------------------------------
// attention logits el/er per (node, head) from node-major fp16 feat
// ---------------------------------------------------------------------------
__global__ __launch_bounds__(256)
void eler_k(const __half2* __restrict__ feat, const float* __restrict__ al,
            const float* __restrict__ ar, float* __restrict__ el,
            float* __restrict__ er) {
  int i = blockIdx.x * 256 + threadIdx.x;  // over N*8
  if (i >= NN * NHEAD) return;
  int h = i & 7;
  const __half2* f2 = feat + (size_t)i * 8;  // 16 halves per (node,head)
  float sl = 0.f, sr = 0.f;
#pragma unroll
  for (int q = 0; q < 8; ++q) {
    float2 f = __half22float2(f2[q]);
    sl += f.x * al[h * 16 + 2 * q] + f.y * al[h * 16 + 2 * q + 1];
    sr += f.x * ar[h * 16 + 2 * q] + f.y * ar[h * 16 + 2 * q + 1];
  }
  el[i] = sl; er[i] = sr;
}

// ---------------------------------------------------------------------------
// CSR build
// ---------------------------------------------------------------------------
__global__ __launch_bounds__(256)
void hist_k(const int* __restrict__ dst, int* __restrict__ deg) {
  int e = blockIdx.x * 256 + threadIdx.x;
  if (e < EE) atomicAdd(&deg[dst[e]], 1);
}

__global__ __launch_bounds__(256)
void scan_block_k(const int* __restrict__ in, int* __restrict__ out,
                  int* __restrict__ bsums, int n) {
  __shared__ int sh[256];
  int i = blockIdx.x * 256 + threadIdx.x;
  int v = (i < n) ? in[i] : 0;
  sh[threadIdx.x] = v;
  __syncthreads();
#pragma unroll
  for (int off = 1; off < 256; off <<= 1) {
    int t = (threadIdx.x >= off) ? sh[threadIdx.x - off] : 0;
    __syncthreads();
    sh[threadIdx.x] += t;
    __syncthreads();
  }
  if (i < n) out[i] = sh[threadIdx.x] - v;  // exclusive
  if (threadIdx.x == 255) bsums[blockIdx.x] = sh[255];
}

__global__ __launch_bounds__(256)
void scan_bsums_k(int* bsums, int nb) {
  __shared__ int sh[256];
  int v = (threadIdx.x < nb) ? bsums[threadIdx.x] : 0;
  sh[threadIdx.x] = v;
  __syncthreads();
#pragma unroll
  for (int off = 1; off < 256; off <<= 1) {
    int t = (threadIdx.x >= off) ? sh[threadIdx.x - off] : 0;
    __syncthreads();
    sh[threadIdx.x] += t;
    __syncthreads();
  }
  if (threadIdx.x < nb) bsums[threadIdx.x] = sh[threadIdx.x] - v;
}

__global__ __launch_bounds__(256)
void add_off_k(int* __restrict__ out, const int* __restrict__ bsums, int n) {
  int i = blockIdx.x * 256 + threadIdx.x;
  if (i < n) out[i] += bsums[blockIdx.x];
  if (i == 0) out[n] = EE;
}

__global__ __launch_bounds__(256)
void fill_k(const int* __restrict__ src, const int* __restrict__ dst,
            const int* __restrict__ rowptr, int* __restrict__ cnt,
            int* __restrict__ csrsrc) {
  int e = blockIdx.x * 256 + threadIdx.x;
  if (e >= EE) return;
  int d = dst[e];
  int p = rowptr[d] + atomicAdd(&cnt[d], 1);
  csrsrc[p] = src[e];
}

// ---------------------------------------------------------------------------
// GAT aggregate, both relations fused. One wave per dst node; lane owns
// feature pair (2*lane, 2*lane+1) in head lane>>3. Branch-free 4-edge batched
// pipeline: 12 independent loads in flight per group, then 4 serial online-
// softmax updates. Tail padding: clamped idx + e=-1e30 => p underflows to 0.
// ---------------------------------------------------------------------------
__device__ __forceinline__ float2 agg_rel(const __half2* __restrict__ feat,
                                          const float* __restrict__ el,
                                          float er_h,
                                          const int* __restrict__ csr,
                                          int beg, int end, int lane, int head) {
  float m = -1e30f, ls = 0.f, a0 = 0.f, a1 = 0.f;
  for (int t = beg; t < end; t += 4) {
    int s[4];
#pragma unroll
    for (int j = 0; j < 4; ++j) {
      int idx = t + j;
      s[j] = csr[(idx < end) ? idx : (end - 1)];
    }
    float ev[4];
#pragma unroll
    for (int j = 0; j < 4; ++j) ev[j] = el[(size_t)s[j] * 8 + head];
    __half2 f[4];
#pragma unroll
    for (int j = 0; j < 4; ++j) f[j] = feat[(size_t)s[j] * 64 + lane];
#pragma unroll
    for (int j = 0; j < 4; ++j) {
      float e = ev[j] + er_h;
      e = (e > 0.f) ? e : 0.2f * e;            // leaky_relu 0.2
      e = (t + j < end) ? e : -1e30f;          // padded edge -> p = 0
      float mn = fmaxf(m, e);
      float scl = __expf(m - mn);
      float p = __expf(e - mn);
      float2 fv = __half22float2(f[j]);
      ls = ls * scl + p;
      a0 = a0 * scl + p * fv.x;
      a1 = a1 * scl + p * fv.y;
      m = mn;
    }
  }
  float inv = (ls > 0.f) ? 1.f / ls : 0.f;     // isolated node -> rst = 0
  return make_float2(a0 * inv, a1 * inv);
}

__global__ __launch_bounds__(256)
void gat_agg_fused_k(const __half2* __restrict__ f0, const __half2* __restrict__ f1,
                     const float* __restrict__ el0, const float* __restrict__ er0,
                     const float* __restrict__ el1, const float* __restrict__ er1,
                     const int* __restrict__ rp0, const int* __restrict__ cs0,
                     const int* __restrict__ rp1, const int* __restrict__ cs1,
                     const float* __restrict__ b0, const float* __restrict__ b1,
                     float* __restrict__ h1, _Float16* __restrict__ h1h) {
  int n = blockIdx.x * 4 + (threadIdx.x >> 6);
  if (n >= NN) return;
  int lane = threadIdx.x & 63;
  int head = lane >> 3;
  float2 r0 = agg_rel(f0, el0, er0[(size_t)n * 8 + head], cs0,
                      rp0[n], rp0[n + 1], lane, head);
  float2 r1 = agg_rel(f1, el1, er1[(size_t)n * 8 + head], cs1,
                      rp1[n], rp1[n + 1], lane, head);
  float t0 = r0.x + r1.x + b0[lane * 2] + b1[lane * 2];
  float t1 = r0.y + r1.y + b0[lane * 2 + 1] + b1[lane * 2 + 1];
  t0 = (t0 > 0.f) ? t0 : 0.01f * t0;           // leaky_relu 0.01
  t1 = (t1 > 0.f) ? t1 : 0.01f * t1;
  float2* h2p = (float2*)h1 + (size_t)n * 64 + lane;
  float2 h = *h2p;
  h.x += t0; h.y += t1;
  *h2p = h;
  __half2* hh = (__half2*)h1h + (size_t)n * 64 + lane;
  *hh = __floats2half2_rn(h.x, h.y);
}

// ---------------------------------------------------------------------------
extern "C" void kernel_launch(void* const* d_in, const int* in_sizes, int n_in,
                              void* d_out, int out_size, void* d_ws,
                              size_t ws_size, hipStream_t stream) {
  const float* inputs = (const float*)d_in[0];
  const int* src = (const int*)d_in[1];
  const int* dst = (const int*)d_in[2];
  const float* ew1 = (const float*)d_in[3];
  const float* eg = (const float*)d_in[4];
  const float* eb = (const float*)d_in[5];
  const float* ew2 = (const float*)d_in[6];
  const float* gfc = (const float*)d_in[7];
  const float* gal = (const float*)d_in[8];
  const float* gar = (const float*)d_in[9];
  const float* gb = (const float*)d_in[10];
  const float* dw1 = (const float*)d_in[11];
  const float* dg = (const float*)d_in[12];
  const float* db = (const float*)d_in[13];
  const float* dw2 = (const float*)d_in[14];
  float* out = (float*)d_out;

  // ---- workspace layout ----
  char* p = (char*)d_ws;
  float* h1 = (float*)p;            p += (size_t)NN * 128 * 4;   // 25.6MB
  _Float16* h1h = (_Float16*)p;     p += (size_t)NN * 128 * 2;   // 12.8MB
  // region C (25.6MB): ybuf (MLP phases) | feat0h+feat1h (GAT phase)
  float* ybuf = (float*)p;
  _Float16* feat0h = (_Float16*)p;
  _Float16* feat1h = feat0h + (size_t)NN * 128;
  p += (size_t)NN * 128 * 4;
  // region D (12.8MB): ybuf_h (MLP phases) | el/er (GAT phase, node-major)
  _Float16* ybuf_h = (_Float16*)p;
  float* el0 = (float*)p;
  float* er0 = el0 + (size_t)NN * NHEAD;
  float* el1 = er0 + (size_t)NN * NHEAD;
  float* er1 = el1 + (size_t)NN * NHEAD;
  p += (size_t)NN * 128 * 2;
  float* stats = (float*)p;         p += 512 * 4;
  _Float16* wt = (_Float16*)p;      p += (size_t)(10 * 16384 + 4096) * 2;
  _Float16* ew2t = wt;
  _Float16* dw1t = wt + 9 * 16384;
  _Float16* dw2t = wt + 10 * 16384;
  int* rowptr0 = (int*)p;           p += (NN + 1) * 4;
  int* rowptr1 = (int*)p;           p += (NN + 1) * 4;
  int* csr0 = (int*)p;              p += (size_t)EE * 4;
  int* csr1 = (int*)p;              p += (size_t)EE * 4;
  int* cnt = (int*)p;               p += NN * 4;
  int* bsums = (int*)p;
  int* rowptr[2] = {rowptr0, rowptr1};
  int* csr[2] = {csr0, csr1};

  const int SCB = (NN + 255) / 256;   // 196
  const int EGB = (EE + 255) / 256;   // 3125
  const int GB = (NN + 127) / 128;    // 391

  // ---- CSR build per relation ----
  for (int r = 0; r < 2; ++r) {
    hipMemsetAsync(cnt, 0, NN * sizeof(int), stream);
    hist_k<<<EGB, 256, 0, stream>>>(dst + (size_t)r * EE, cnt);
    scan_block_k<<<SCB, 256, 0, stream>>>(cnt, rowptr[r], bsums, NN);
    scan_bsums_k<<<1, 256, 0, stream>>>(bsums, SCB);
    add_off_k<<<SCB, 256, 0, stream>>>(rowptr[r], bsums, NN);
    hipMemsetAsync(cnt, 0, NN * sizeof(int), stream);
    fill_k<<<EGB, 256, 0, stream>>>(src + (size_t)r * EE, dst + (size_t)r * EE,
                                    rowptr[r], cnt, csr[r]);
  }

  // ---- transpose+convert all 11 weight matrices (one launch) ----
  {
    TJobs jobs;
    jobs.j[0] = {ew2, ew2t, 128, 128};
    for (int i = 0; i < 8; ++i)
      jobs.j[1 + i] = {gfc + (size_t)i * 16384, wt + (size_t)(1 + i) * 16384, 128, 128};
    jobs.j[9] = {dw1, dw1t, 128, 128};
    jobs.j[10] = {dw2, dw2t, 128, 32};
    transpose_k<<<11, 256, 0, stream>>>(jobs);
  }

  // ---- embed MLP: h = relu(bn(x@w1)); h1 = h@w2 + h ----
  gemm_f32_k<<<GB, 256, 0, stream>>>(inputs, ew1, ybuf, NN);
  hipMemsetAsync(stats, 0, 512 * sizeof(float), stream);
  bn_stats_k<<<(NN + 63) / 64, 256, 0, stream>>>(ybuf, stats, NN);
  bn_final_k<<<1, 128, 0, stream>>>(stats, eg, eb);
  bn_apply_k<<<(NN * 32 + 255) / 256, 256, 0, stream>>>(ybuf, stats, ybuf, ybuf_h, NN);
  mfma_gemm_k<128, true, true, true><<<GB, 256, 0, stream>>>(
      ybuf_h, ew2t, ybuf, h1h, h1, NN);

  // ---- 4 GAT layers ----
  for (int l = 0; l < 4; ++l) {
    _Float16* wt0 = wt + (size_t)(1 + l * 2 + 0) * 16384;
    _Float16* wt1 = wt + (size_t)(1 + l * 2 + 1) * 16384;
    mfma_gemm_k<128, true, false, false><<<GB, 256, 0, stream>>>(
        h1h, wt0, nullptr, feat0h, nullptr, NN);
    mfma_gemm_k<128, true, false, false><<<GB, 256, 0, stream>>>(
        h1h, wt1, nullptr, feat1h, nullptr, NN);
    eler_k<<<(NN * 8 + 255) / 256, 256, 0, stream>>>(
        (const __half2*)feat0h, gal + (size_t)(l * 2 + 0) * HIDF,
        gar + (size_t)(l * 2 + 0) * HIDF, el0, er0);
    eler_k<<<(NN * 8 + 255) / 256, 256, 0, stream>>>(
        (const __half2*)feat1h, gal + (size_t)(l * 2 + 1) * HIDF,
        gar + (size_t)(l * 2 + 1) * HIDF, el1, er1);
    gat_agg_fused_k<<<(NN + 3) / 4, 256, 0, stream>>>(
        (const __half2*)feat0h, (const __half2*)feat1h, el0, er0, el1, er1,
        rowptr[0], csr[0], rowptr[1], csr[1],
        gb + (size_t)(l * 2 + 0) * HIDF, gb + (size_t)(l * 2 + 1) * HIDF,
        h1, h1h);
  }

  // ---- decision MLP: out = relu(bn(h1@w1)) @ w2 ----
  mfma_gemm_k<128, false, true, false><<<GB, 256, 0, stream>>>(
      h1h, dw1t, nullptr, nullptr, ybuf, NN);
  hipMemsetAsync(stats, 0, 512 * sizeof(float), stream);
  bn_stats_k<<<(NN + 63) / 64, 256, 0, stream>>>(ybuf, stats, NN);
  bn_final_k<<<1, 128, 0, stream>>>(stats, dg, db);
  bn_apply_k<<<(NN * 32 + 255) / 256, 256, 0, stream>>>(ybuf, stats, ybuf, ybuf_h, NN);
  mfma_gemm_k<32, false, true, false><<<GB, 256, 0, stream>>>(
      ybuf_h, dw2t, nullptr, nullptr, out, NN);
}